// Round 6
// baseline (223.415 us; speedup 1.0000x reference)
//
#include <hip/hip_runtime.h>
#include <math.h>

#define NN 50000
#define NE 800000
#define DM 128
#define NH 8
#define FF 512
#define NBLK 391    // ceil(50000/128)
#define NBLK64 782  // ceil(50000/64)

// merged prep kernel block ranges
#define PB_X    6250          // x->bf16 blocks
#define PB_WT   192           // weight transpose blocks
#define PB_RP   196           // rowptr blocks
#define PB_EMB  1563          // embn blocks
#define PB_TOT  (PB_X + PB_WT + PB_RP + PB_EMB)

typedef __attribute__((ext_vector_type(8))) short bf16x8;
typedef __attribute__((ext_vector_type(4))) float f32x4;

__device__ __forceinline__ short f2bf(float f) {
    union { float f; unsigned u; } v; v.f = f;
    unsigned r = v.u + 0x7fff + ((v.u >> 16) & 1);
    return (short)(r >> 16);
}
__device__ __forceinline__ float bf2f(short s) {
    union { unsigned u; float f; } v; v.u = ((unsigned)(unsigned short)s) << 16;
    return v.f;
}
__device__ __forceinline__ float u2f(unsigned u) {
    union { unsigned u; float f; } v; v.u = u; return v.f;
}

// fast gelu (tanh form, |err| < ~4e-4 abs; post-W2 impact ~1e-4 << bf16 noise)
__device__ __forceinline__ float gelu_f(float x) {
    float u = x * (0.7978845608f + 0.0356774081f * x * x);
    float t = 1.f - 2.f / (__expf(2.f * u) + 1.f);
    return 0.5f * x * (1.f + t);
}

// ---------------------------------------------------------------------------
__device__ __forceinline__ void gload16(const void* g, void* l) {
    __builtin_amdgcn_global_load_lds(
        (const __attribute__((address_space(1))) void*)g,
        (__attribute__((address_space(3))) void*)l, 16, 0, 0);
}

// Stage 128x128 bf16 tile with XOR swizzle (inverse-swizzled global source +
// linear LDS dest; reads apply same XOR — rule #21).
__device__ __forceinline__ void stage_tile(const short* __restrict__ src, int row0,
                                           int maxrow, int ld, int col0,
                                           short* sm) {
    const int tid = threadIdx.x;
    const int w = tid >> 6, l = tid & 63;
    const int p = l & 15;
    #pragma unroll
    for (int j = 0; j < 8; ++j) {
        int lr = w * 32 + j * 4 + (l >> 4);
        int gr = row0 + lr; gr = gr > maxrow ? maxrow : gr;
        int s = p ^ (lr & 7);
        const short* g = src + (size_t)gr * ld + col0 + s * 8;
        gload16(g, sm + (w * 32 + j * 4) * 128);
    }
}

__device__ __forceinline__ void stage_tile64(const short* __restrict__ src, int row0,
                                             int maxrow, int ld, int col0,
                                             short* sm) {
    const int tid = threadIdx.x;
    const int w = tid >> 6, l = tid & 63;
    const int p = l & 15;
    #pragma unroll
    for (int j = 0; j < 4; ++j) {
        int lr = w * 16 + j * 4 + (l >> 4);
        int gr = row0 + lr; gr = gr > maxrow ? maxrow : gr;
        int s = p ^ (lr & 7);
        const short* g = src + (size_t)gr * ld + col0 + s * 8;
        gload16(g, sm + (w * 16 + j * 4) * 128);
    }
}

__device__ __forceinline__ bf16x8 frag_ld(const short* sm, int outer, int slot) {
    return *(const bf16x8*)(sm + outer * 128 + ((slot ^ (outer & 7)) << 3));
}

__device__ __forceinline__ void mfma_tile(const short* sA, const short* sB,
                                          int wm, int wn, int lane,
                                          f32x4 acc[4][4]) {
    const int l15 = lane & 15, l4 = lane >> 4;
    #pragma unroll
    for (int ks = 0; ks < 4; ++ks) {
        bf16x8 a[4], b[4];
        int slot = ks * 4 + l4;
        #pragma unroll
        for (int f = 0; f < 4; ++f) a[f] = frag_ld(sA, wm * 64 + f * 16 + l15, slot);
        #pragma unroll
        for (int f = 0; f < 4; ++f) b[f] = frag_ld(sB, wn * 64 + f * 16 + l15, slot);
        #pragma unroll
        for (int fm = 0; fm < 4; ++fm)
            #pragma unroll
            for (int fn = 0; fn < 4; ++fn)
                acc[fm][fn] = __builtin_amdgcn_mfma_f32_16x16x32_bf16(
                    a[fm], b[fn], acc[fm][fn], 0, 0, 0);
    }
}

// A-tile 64 rows (m), B-tile 128 rows (n): wave (wm over m 2x32, wn over n 2x64)
__device__ __forceinline__ void mfma_tile64(const short* sA, const short* sB,
                                            int wm, int wn, int lane,
                                            f32x4 acc[2][4]) {
    const int l15 = lane & 15, l4 = lane >> 4;
    #pragma unroll
    for (int ks = 0; ks < 4; ++ks) {
        bf16x8 a[2], b[4];
        int slot = ks * 4 + l4;
        #pragma unroll
        for (int f = 0; f < 2; ++f) a[f] = frag_ld(sA, wm * 32 + f * 16 + l15, slot);
        #pragma unroll
        for (int f = 0; f < 4; ++f) b[f] = frag_ld(sB, wn * 64 + f * 16 + l15, slot);
        #pragma unroll
        for (int fm = 0; fm < 2; ++fm)
            #pragma unroll
            for (int fn = 0; fn < 4; ++fn)
                acc[fm][fn] = __builtin_amdgcn_mfma_f32_16x16x32_bf16(
                    a[fm], b[fn], acc[fm][fn], 0, 0, 0);
    }
}

// Swapped-operand GEMM1: A = W1T chunk (128 ff rows), B = h-tile (64 m rows).
// acc[fa][fb]: D rows = ff (wm over 2x64), D cols = m (wn over 2x32).
__device__ __forceinline__ void mfma_tile_ff(const short* sA, const short* sB,
                                             int wm, int wn, int lane,
                                             f32x4 acc[4][2]) {
    const int l15 = lane & 15, l4 = lane >> 4;
    #pragma unroll
    for (int ks = 0; ks < 4; ++ks) {
        bf16x8 a[4], b[2];
        int slot = ks * 4 + l4;
        #pragma unroll
        for (int f = 0; f < 4; ++f) a[f] = frag_ld(sA, wm * 64 + f * 16 + l15, slot);
        #pragma unroll
        for (int f = 0; f < 2; ++f) b[f] = frag_ld(sB, wn * 32 + f * 16 + l15, slot);
        #pragma unroll
        for (int fa = 0; fa < 4; ++fa)
            #pragma unroll
            for (int fb = 0; fb < 2; ++fb)
                acc[fa][fb] = __builtin_amdgcn_mfma_f32_16x16x32_bf16(
                    a[fa], b[fb], acc[fa][fb], 0, 0, 0);
    }
}

// ---------------------------------------------------------------------------
// Merged prep: x->bf16 | 6 weight transposes | rowptr | embn materialization.
__global__ __launch_bounds__(256) void k_prep(
    const float* __restrict__ x, short* __restrict__ xb,
    const float* __restrict__ Wq, const float* __restrict__ Wk,
    const float* __restrict__ Wv, const float* __restrict__ Wo,
    const float* __restrict__ W1, const float* __restrict__ W2,
    short* __restrict__ wts,
    const int* __restrict__ row, int* __restrict__ rowptr,
    const int* __restrict__ db, const float* __restrict__ emb,
    float* __restrict__ embn)
{
    int bid = blockIdx.x;
    const int tid = threadIdx.x;

    if (bid < PB_X) {
        int i = bid * 256 + tid;
        if (i < NN * DM / 4) {
            float4 v = ((const float4*)x)[i];
            ((short4*)xb)[i] = make_short4(f2bf(v.x), f2bf(v.y), f2bf(v.z), f2bf(v.w));
        }
        return;
    }
    bid -= PB_X;
    if (bid < PB_WT) {
        const float* W; short* Wt; int K, N, bx, by;
        if (bid < 64) {
            int wsel = bid >> 4, rel = bid & 15;
            W = wsel == 0 ? Wq : wsel == 1 ? Wk : wsel == 2 ? Wv : Wo;
            Wt = wts + wsel * 16384; K = 128; N = 128; bx = rel & 3; by = rel >> 2;
        } else if (bid < 128) {
            int rel = bid - 64;
            W = W1; Wt = wts + 65536; K = 128; N = 512; bx = rel & 15; by = rel >> 4;
        } else {
            int rel = bid - 128;
            W = W2; Wt = wts + 131072; K = 512; N = 128; bx = rel & 3; by = rel >> 2;
        }
        __shared__ float t[32][33];
        int n0 = bx * 32, k0 = by * 32;
        int r = tid >> 3, c4 = (tid & 7) * 4;
        float4 v = *(const float4*)(W + (size_t)(k0 + r) * N + n0 + c4);
        t[r][c4 + 0] = v.x; t[r][c4 + 1] = v.y; t[r][c4 + 2] = v.z; t[r][c4 + 3] = v.w;
        __syncthreads();
        short4 o = make_short4(f2bf(t[c4 + 0][r]), f2bf(t[c4 + 1][r]),
                               f2bf(t[c4 + 2][r]), f2bf(t[c4 + 3][r]));
        *(short4*)(Wt + (size_t)(n0 + r) * K + k0 + c4) = o;
        return;
    }
    bid -= PB_WT;
    if (bid < PB_RP) {
        int n = bid * 256 + tid;
        if (n > NN) return;
        int lo = 0, hi = NE;
        while (lo < hi) {
            int mid = (lo + hi) >> 1;
            if (row[mid] < n) lo = mid + 1; else hi = mid;
        }
        rowptr[n] = lo;
        return;
    }
    bid -= PB_RP;
    {
        int i = bid * 256 + tid;
        if (i < NN * NH) embn[i] = emb[db[i >> 3] * NH + (i & 7)];
    }
}

// ---------------------------------------------------------------------------
__global__ __launch_bounds__(256) void k_gemm_qkv(
    const short* __restrict__ xb, const short* __restrict__ Wt,
    const float* __restrict__ bq, const float* __restrict__ bk,
    const float* __restrict__ bv,
    short* __restrict__ Qb, short* __restrict__ Kb, short* __restrict__ Vb)
{
    __shared__ short sm[2 * 16384];
    const int tid = threadIdx.x, lane = tid & 63, wid = tid >> 6;
    const int wm = wid >> 1, wn = wid & 1;
    const int r0 = blockIdx.x * 128;

    stage_tile(xb, r0, NN - 1, 128, 0, sm);
    #pragma unroll
    for (int m = 0; m < 3; ++m) {
        if (m) __syncthreads();
        stage_tile(Wt + m * 16384, 0, 127, 128, 0, sm + 16384);
        __syncthreads();
        f32x4 acc[4][4];
        #pragma unroll
        for (int i = 0; i < 4; ++i)
            #pragma unroll
            for (int j = 0; j < 4; ++j)
                acc[i][j] = (f32x4){0.f, 0.f, 0.f, 0.f};
        mfma_tile(sm, sm + 16384, wm, wn, lane, acc);

        const float* bias = m == 0 ? bq : (m == 1 ? bk : bv);
        short* out = m == 0 ? Qb : (m == 1 ? Kb : Vb);
        #pragma unroll
        for (int fn = 0; fn < 4; ++fn) {
            int col = wn * 64 + fn * 16 + (lane & 15);
            float bc = bias[col];
            #pragma unroll
            for (int fm = 0; fm < 4; ++fm) {
                int rowb = r0 + wm * 64 + fm * 16 + (lane >> 4) * 4;
                #pragma unroll
                for (int rr = 0; rr < 4; ++rr) {
                    int gr = rowb + rr;
                    if (gr < NN)
                        out[(size_t)gr * DM + col] = f2bf(acc[fm][fn][rr] + bc);
                }
            }
        }
    }
}

// ---------------------------------------------------------------------------
// Wave-per-node fused attention, 16-edge chunks, V preloaded alongside K.
__global__ __launch_bounds__(256) void k_attn_wave(
    const short* __restrict__ Qb, const short* __restrict__ Kb,
    const short* __restrict__ Vb, const int* __restrict__ col,
    const int* __restrict__ rowptr, const float* __restrict__ embn,
    short* __restrict__ aggb)
{
    const int lane = threadIdx.x & 63;
    const int n = blockIdx.x * 4 + (threadIdx.x >> 6);
    const int e0 = rowptr[n], e1 = rowptr[n + 1];
    const int s = lane >> 3, h = lane & 7;
    const int h2 = lane >> 3;

    float qf[16];
    {
        const bf16x8* qp = (const bf16x8*)(Qb + (size_t)n * DM + h * 16);
        bf16x8 q0 = qp[0], q1 = qp[1];
        #pragma unroll
        for (int j = 0; j < 8; ++j) { qf[j] = bf2f(q0[j]); qf[8 + j] = bf2f(q1[j]); }
    }
    const float embr = embn[(size_t)n * NH + h];

    float m = -INFINITY, l = 0.f, acc0 = 0.f, acc1 = 0.f;

    for (int c0 = e0; c0 < e1; c0 += 16) {
        int ea = c0 + s, eb = c0 + 8 + s;
        bool va = ea < e1, vb = eb < e1;
        int ca = col[va ? ea : e1 - 1];
        int cb = col[vb ? eb : e1 - 1];

        const bf16x8* kpa = (const bf16x8*)(Kb + (size_t)ca * DM + h * 16);
        const bf16x8* kpb = (const bf16x8*)(Kb + (size_t)cb * DM + h * 16);
        bf16x8 ka0 = kpa[0], ka1 = kpa[1];
        bf16x8 kb0 = kpb[0], kb1 = kpb[1];
        float ema = embn[(size_t)ca * NH + h];
        float emB = embn[(size_t)cb * NH + h];

        int nv = e1 - c0; nv = nv > 16 ? 16 : nv;
        unsigned vv[16];
        #pragma unroll
        for (int j = 0; j < 8; ++j) {
            int cj = __shfl(ca, j * 8);
            vv[j] = (j < nv) ? *(const unsigned*)(Vb + (size_t)cj * DM + lane * 2) : 0u;
        }
        #pragma unroll
        for (int j = 0; j < 8; ++j) {
            int cj = __shfl(cb, j * 8);
            vv[8 + j] = (8 + j < nv) ? *(const unsigned*)(Vb + (size_t)cj * DM + lane * 2) : 0u;
        }

        float da = 0.f, dbv = 0.f;
        #pragma unroll
        for (int j = 0; j < 8; ++j) {
            da  += qf[j] * bf2f(ka0[j]) + qf[8 + j] * bf2f(ka1[j]);
            dbv += qf[j] * bf2f(kb0[j]) + qf[8 + j] * bf2f(kb1[j]);
        }
        float sa = va ? da * 0.25f + embr + ema : -INFINITY;
        float sb = vb ? dbv * 0.25f + embr + emB : -INFINITY;

        float mc = fmaxf(sa, sb);
        mc = fmaxf(mc, __shfl_xor(mc, 8));
        mc = fmaxf(mc, __shfl_xor(mc, 16));
        mc = fmaxf(mc, __shfl_xor(mc, 32));
        float mn = fmaxf(m, mc);
        float f = __expf(m - mn);
        m = mn;
        float pa = __expf(sa - mn);
        float pb = __expf(sb - mn);
        float ps = pa + pb;
        ps += __shfl_xor(ps, 8);
        ps += __shfl_xor(ps, 16);
        ps += __shfl_xor(ps, 32);
        l = l * f + ps;

        float fr = __shfl(f, h2);
        acc0 *= fr; acc1 *= fr;
        #pragma unroll
        for (int j = 0; j < 8; ++j) {
            float pj = __shfl(pa, j * 8 + h2);
            acc0 += pj * u2f(vv[j] << 16);
            acc1 += pj * u2f(vv[j] & 0xffff0000u);
        }
        #pragma unroll
        for (int j = 0; j < 8; ++j) {
            float pj = __shfl(pb, j * 8 + h2);
            acc0 += pj * u2f(vv[8 + j] << 16);
            acc1 += pj * u2f(vv[8 + j] & 0xffff0000u);
        }
    }
    float la = __shfl(l, h2);
    la = fmaxf(la, 1e-12f);
    unsigned o = ((unsigned)(unsigned short)f2bf(acc0 / la)) |
                 (((unsigned)(unsigned short)f2bf(acc1 / la)) << 16);
    *(unsigned*)(aggb + (size_t)n * DM + lane * 2) = o;
}

// ---------------------------------------------------------------------------
// agg@Wo + bo + x -> LN1 -> h (f32) and hb (bf16)
__global__ __launch_bounds__(256) void k_gemm_ln1(
    const short* __restrict__ aggb, const short* __restrict__ Wot,
    const float* __restrict__ bo, const float* __restrict__ x,
    const float* __restrict__ g, const float* __restrict__ b,
    float* __restrict__ h, short* __restrict__ hb)
{
    __shared__ union { short ab[2 * 16384]; float hs[128 * 129]; } u;
    __shared__ float mu[128], rsd[128];
    const int tid = threadIdx.x, lane = tid & 63, wid = tid >> 6;
    const int wm = wid >> 1, wn = wid & 1;
    const int r0 = blockIdx.x * 128;

    stage_tile(aggb, r0, NN - 1, 128, 0, u.ab);
    stage_tile(Wot, 0, 127, 128, 0, u.ab + 16384);
    __syncthreads();

    f32x4 acc[4][4];
    #pragma unroll
    for (int i = 0; i < 4; ++i)
        #pragma unroll
        for (int j = 0; j < 4; ++j) acc[i][j] = (f32x4){0.f, 0.f, 0.f, 0.f};
    mfma_tile(u.ab, u.ab + 16384, wm, wn, lane, acc);
    __syncthreads();

    #pragma unroll
    for (int fn = 0; fn < 4; ++fn) {
        int col = wn * 64 + fn * 16 + (lane & 15);
        float bc = bo[col];
        #pragma unroll
        for (int fm = 0; fm < 4; ++fm) {
            int rowb = wm * 64 + fm * 16 + (lane >> 4) * 4;
            #pragma unroll
            for (int rr = 0; rr < 4; ++rr) {
                int r_ = rowb + rr, gr = r0 + r_;
                float xr = (gr < NN) ? x[(size_t)gr * DM + col] : 0.f;
                u.hs[r_ * 129 + col] = acc[fm][fn][rr] + bc + xr;
            }
        }
    }
    __syncthreads();

    {
        int rrow = tid >> 1, half = tid & 1;
        float s = 0.f, q = 0.f;
        #pragma unroll 8
        for (int c = 0; c < 64; ++c) {
            float v = u.hs[rrow * 129 + half * 64 + c];
            s += v; q += v * v;
        }
        s += __shfl_xor(s, 1);
        q += __shfl_xor(q, 1);
        float m = s * (1.f / DM);
        float var = q * (1.f / DM) - m * m;
        if (half == 0) { mu[rrow] = m; rsd[rrow] = rsqrtf(var + 1e-5f); }
    }
    __syncthreads();

    for (int i = 0; i < 64; ++i) {
        int idx = i * 256 + tid;
        int rrow = idx >> 7, c = idx & 127;
        int gr = r0 + rrow;
        if (gr < NN) {
            float v = (u.hs[rrow * 129 + c] - mu[rrow]) * rsd[rrow] * g[c] + b[c];
            h[(size_t)gr * DM + c] = v;
            hb[(size_t)gr * DM + c] = f2bf(v);
        }
    }
}

// ---------------------------------------------------------------------------
// Fused FFN: gelu(hb@W1+b1)@W2 + b2 + h -> LN2 -> out.  BM=64, 64KB dyn LDS.
// GEMM1 runs operand-swapped (A=W1T, B=h) so each lane's D-frag holds 4
// K-contiguous ff values at fixed m -> packed ds_write_b64 into C (2-way max).
__global__ __launch_bounds__(256) void k_ffn_fused(
    const short* __restrict__ hb, const short* __restrict__ Wt1,
    const float* __restrict__ b1, const short* __restrict__ Wt2,
    const float* __restrict__ b2, const float* __restrict__ h,
    const float* __restrict__ g, const float* __restrict__ bb,
    float* __restrict__ out)
{
    extern __shared__ char smraw[];
    short* A = (short*)smraw;          // 16 KB: h tile 64x128
    short* B = A + 8192;               // 32 KB: weight chunk 128x128
    short* C = B + 16384;              // 16 KB: ff tile 64m x 128ff
    float* hs = (float*)smraw;         // overlay after gemms
    __shared__ float mu[64], rsd[64];

    const int tid = threadIdx.x, lane = tid & 63, wid = tid >> 6;
    const int wm = wid >> 1, wn = wid & 1;
    const int r0 = blockIdx.x * 64;

    f32x4 acc2[2][4];
    #pragma unroll
    for (int i = 0; i < 2; ++i)
        #pragma unroll
        for (int j = 0; j < 4; ++j) acc2[i][j] = (f32x4){0.f, 0.f, 0.f, 0.f};

    stage_tile64(hb, r0, NN - 1, 128, 0, A);

    for (int kc = 0; kc < 4; ++kc) {
        if (kc) __syncthreads();                    // prev mfma2 done with B,C
        stage_tile(Wt1, kc * 128, FF - 1, 128, 0, B);
        __syncthreads();                            // A (first iter) + W1c ready

        f32x4 accf[4][2];
        #pragma unroll
        for (int i = 0; i < 4; ++i)
            #pragma unroll
            for (int j = 0; j < 2; ++j) accf[i][j] = (f32x4){0.f, 0.f, 0.f, 0.f};
        mfma_tile_ff(B, A, wm, wn, lane, accf);     // rows=ff, cols=m

        // gelu -> C: lane packs 4 contiguous ff values at fixed m, b64 write
        #pragma unroll
        for (int fa = 0; fa < 4; ++fa) {
            int ffb = wm * 64 + fa * 16 + (lane >> 4) * 4;  // ff within chunk
            float4 bc = *(const float4*)(b1 + kc * 128 + ffb);
            #pragma unroll
            for (int fb = 0; fb < 2; ++fb) {
                int m = wn * 32 + fb * 16 + (lane & 15);
                short4 pk;
                pk.x = f2bf(gelu_f(accf[fa][fb][0] + bc.x));
                pk.y = f2bf(gelu_f(accf[fa][fb][1] + bc.y));
                pk.z = f2bf(gelu_f(accf[fa][fb][2] + bc.z));
                pk.w = f2bf(gelu_f(accf[fa][fb][3] + bc.w));
                int addr = m * 128 + (((ffb >> 3) ^ (m & 7)) << 3) + (ffb & 7);
                *(short4*)(C + addr) = pk;
            }
        }
        __syncthreads();                            // C visible, B free
        stage_tile(Wt2, 0, 127, FF, kc * 128, B);
        __syncthreads();                            // W2c ready
        mfma_tile64(C, B, wm, wn, lane, acc2);      // rows=m, cols=dm
    }
    __syncthreads();                                // all LDS reads done; overlay hs

    #pragma unroll
    for (int fn = 0; fn < 4; ++fn) {
        int col = wn * 64 + fn * 16 + (lane & 15);
        float bc = b2[col];
        #pragma unroll
        for (int fm = 0; fm < 2; ++fm) {
            int rowb = wm * 32 + fm * 16 + (lane >> 4) * 4;
            #pragma unroll
            for (int rr = 0; rr < 4; ++rr) {
                int r_ = rowb + rr, gr = r0 + r_;
                float hr = (gr < NN) ? h[(size_t)gr * DM + col] : 0.f;
                hs[r_ * 129 + col] = acc2[fm][fn][rr] + bc + hr;
            }
        }
    }
    __syncthreads();

    {
        int rrow = tid >> 2, q = tid & 3;
        float s = 0.f, qq = 0.f;
        #pragma unroll 8
        for (int c = 0; c < 32; ++c) {
            float v = hs[rrow * 129 + q * 32 + c];
            s += v; qq += v * v;
        }
        s += __shfl_xor(s, 1);  qq += __shfl_xor(qq, 1);
        s += __shfl_xor(s, 2);  qq += __shfl_xor(qq, 2);
        float m = s * (1.f / DM);
        float var = qq * (1.f / DM) - m * m;
        if (q == 0) { mu[rrow] = m; rsd[rrow] = rsqrtf(var + 1e-5f); }
    }
    __syncthreads();

    for (int i = 0; i < 32; ++i) {
        int idx = i * 256 + tid;
        int rrow = idx >> 7, c = idx & 127;
        int gr = r0 + rrow;
        if (gr < NN)
            out[(size_t)gr * DM + c] =
                (hs[rrow * 129 + c] - mu[rrow]) * rsd[rrow] * g[c] + bb[c];
    }
}

// ---------------------------------------------------------------------------
extern "C" void kernel_launch(void* const* d_in, const int* in_sizes, int n_in,
                              void* d_out, int out_size, void* d_ws, size_t ws_size,
                              hipStream_t stream) {
    const float* x   = (const float*)d_in[0];
    const int* row   = (const int*)d_in[1];
    const int* col   = (const int*)d_in[2];
    const int* db    = (const int*)d_in[3];
    const float* Wq  = (const float*)d_in[4];
    const float* bq  = (const float*)d_in[5];
    const float* Wk  = (const float*)d_in[6];
    const float* bk  = (const float*)d_in[7];
    const float* Wv  = (const float*)d_in[8];
    const float* bv  = (const float*)d_in[9];
    const float* Wo  = (const float*)d_in[10];
    const float* bo  = (const float*)d_in[11];
    const float* emb = (const float*)d_in[12];
    const float* g1  = (const float*)d_in[13];
    const float* b1n = (const float*)d_in[14];
    const float* g2  = (const float*)d_in[15];
    const float* b2n = (const float*)d_in[16];
    const float* W1  = (const float*)d_in[17];
    const float* b1  = (const float*)d_in[18];
    const float* W2  = (const float*)d_in[19];
    const float* b2  = (const float*)d_in[20];

    char* W = (char*)d_ws;
    float* embn   = (float*)(W + 0);             // 1.6 MB (free zone)
    short* aggb   = (short*)(W + 25600000);
    short* xb     = (short*)(W + 38400000);
    short* Qb     = (short*)(W + 51200000);
    short* Kb     = (short*)(W + 64000000);
    float* h      = (float*)(W + 51200000);      // overlay (Qb/Kb dead)
    short* Vb     = (short*)(W + 76800000);
    short* hb     = (short*)(W + 76800000);      // overlay (Vb dead)
    short* wts    = (short*)(W + 89600000);
    int* rowptr   = (int*)(W + 89993216);

    k_prep<<<PB_TOT, 256, 0, stream>>>(x, xb, Wq, Wk, Wv, Wo, W1, W2, wts,
                                       row, rowptr, db, emb, embn);
    k_gemm_qkv<<<NBLK, 256, 0, stream>>>(xb, wts, bq, bk, bv, Qb, Kb, Vb);
    k_attn_wave<<<NN / 4, 256, 0, stream>>>(Qb, Kb, Vb, col, rowptr, embn, aggb);
    k_gemm_ln1<<<NBLK, 256, 0, stream>>>(aggb, wts + 49152, bo, x, g1, b1n, h, hb);
    k_ffn_fused<<<NBLK64, 256, 65536, stream>>>(hb, wts + 65536, b1,
                                                wts + 131072, b2, h, g2, b2n,
                                                (float*)d_out);
}